// Round 3
// baseline (309.435 us; speedup 1.0000x reference)
//
#include <hip/hip_runtime.h>

// PatchEmbedder: out[b,p,:] = patch_mask[b,p] ? sum_n sum_l mask_n[b,p,l]*emb_n[ids_n[b,p,l],:] : 0
// B=8, P=1024, D=512, L=(8,7,6).
//
// v3.1 (resubmit of v3 after infra failure; + defensive id clamp):
// FOUR waves per patch, each owning a 512-B quarter-row (one float2 per lane).
//   1. ids+masks fetched LANE-PARALLEL (lane l holds ids[l]) -> 6 loads total,
//      one vmcnt wait, then v_readlane moves them to SGPRs.
//   2. All 21 gathers issue UNCONDITIONALLY back-to-back: masked-off slots are
//      redirected to row 0 (L1-resident broadcast row -> ~0 HBM bytes) instead
//      of being skipped by a scalar branch. No waits, no branches between the
//      21 global_load_dwordx2 -> true 21-deep MLP per wave.
//   3. Accumulate with sc[l] in {0,1}: acc += sc*t (branch-free).
// Staging is 21 x float2 = 42 VGPRs -> ~8 waves/SIMD, 32768 waves total, so
// pmask==0 early-exit waves are backfilled.

#define D_DIM   512
#define NPATCH  8192            // B*P

template <int L>
__device__ __forceinline__ void stage(int vi, int vm,
                                      const float* __restrict__ emb,
                                      int foff,
                                      float2* __restrict__ t,
                                      float* __restrict__ sc) {
#pragma unroll
    for (int l = 0; l < L; ++l) {
        const int sm  = __builtin_amdgcn_readlane(vm, l);   // wave-uniform -> SGPR
        int       sid = __builtin_amdgcn_readlane(vi, l);
        // Dead gathers hit row 0 (L1-hot). Defensive clamp: any id outside the
        // table also goes to row 0 (masked anyway in the reference semantics).
        sid   = (sm && (unsigned)sid < 65536u) ? sid : 0;
        sc[l] = sm ? 1.0f : 0.0f;
        t[l]  = *(const float2*)(emb + (size_t)sid * D_DIM + foff);
    }
}

__global__ __launch_bounds__(256) void patch_embed_kernel(
    const int* __restrict__ ids1, const int* __restrict__ m1, const float* __restrict__ e1,
    const int* __restrict__ ids2, const int* __restrict__ m2, const float* __restrict__ e2,
    const int* __restrict__ ids3, const int* __restrict__ m3, const float* __restrict__ e3,
    const int* __restrict__ pmask, float* __restrict__ out) {
    const int lane  = threadIdx.x & 63;
    const int gw    = (blockIdx.x << 2) | (threadIdx.x >> 6);   // global wave id
    const int patch = __builtin_amdgcn_readfirstlane(gw >> 2);  // 4 waves/patch
    const int foff  = ((gw & 3) << 7) | (lane << 1);            // float idx in row

    float2 acc = make_float2(0.f, 0.f);

    if (__builtin_amdgcn_readfirstlane(pmask[patch])) {   // wave-uniform scalar branch
        // Lane-parallel id/mask fetch: 6 independent dword loads, issued together.
        const int vi1 = ids1[patch * 8 + ((lane < 8) ? lane : 7)];
        const int vm1 = m1  [patch * 8 + ((lane < 8) ? lane : 7)];
        const int vi2 = ids2[patch * 7 + ((lane < 7) ? lane : 6)];
        const int vm2 = m2  [patch * 7 + ((lane < 7) ? lane : 6)];
        const int vi3 = ids3[patch * 6 + ((lane < 6) ? lane : 5)];
        const int vm3 = m3  [patch * 6 + ((lane < 6) ? lane : 5)];

        float2 t[21];
        float  sc[21];
        stage<8>(vi1, vm1, e1, foff, t,      sc);
        stage<7>(vi2, vm2, e2, foff, t + 8,  sc + 8);
        stage<6>(vi3, vm3, e3, foff, t + 15, sc + 15);

        // Reduce after all 21 loads are in flight; results retire in issue order
        // so the compiler can interleave vmcnt(N) waits with the fmacs.
#pragma unroll
        for (int l = 0; l < 21; ++l) {
            acc.x += sc[l] * t[l].x;
            acc.y += sc[l] * t[l].y;
        }
    }

    *(float2*)(out + (size_t)patch * D_DIM + foff) = acc;
}

extern "C" void kernel_launch(void* const* d_in, const int* in_sizes, int n_in,
                              void* d_out, int out_size, void* d_ws, size_t ws_size,
                              hipStream_t stream) {
    // setup_inputs() dict order:
    // 0 ids_1[8,1024,8] i64->int, 1 mask_1[8,1024,8] bool->int, 2 emb_1[65536,512] f32,
    // 3 ids_2[8,1024,7],          4 mask_2[8,1024,7],           5 emb_2[65536,512],
    // 6 ids_3[8,1024,6],          7 mask_3[8,1024,6],           8 emb_3[65536,512],
    // 9 patch_mask[8,1024] bool->int
    const int*   ids1  = (const int*)d_in[0];
    const int*   m1    = (const int*)d_in[1];
    const float* e1    = (const float*)d_in[2];
    const int*   ids2  = (const int*)d_in[3];
    const int*   m2    = (const int*)d_in[4];
    const float* e2    = (const float*)d_in[5];
    const int*   ids3  = (const int*)d_in[6];
    const int*   m3    = (const int*)d_in[7];
    const float* e3    = (const float*)d_in[8];
    const int*   pmask = (const int*)d_in[9];
    float* out = (float*)d_out;

    dim3 grid(NPATCH);   // 8192 blocks x 4 waves = 32768 waves = 4 per patch
    dim3 block(256);
    patch_embed_kernel<<<grid, block, 0, stream>>>(ids1, m1, e1, ids2, m2, e2,
                                                   ids3, m3, e3, pmask, out);
}